// Round 6
// baseline (201.859 us; speedup 1.0000x reference)
//
#include <hip/hip_runtime.h>
#include <hip/hip_fp16.h>
#include <math.h>

// Problem: B=2, S=2048, D=1024, H=16, HD=64, causal attention + RoPE.
// ALL inputs fp32 (reference dtypes), output fp32.
#define B_  2
#define S_  2048
#define D_  1024
#define H_  16
#define HD_ 64

typedef _Float16  f16;
typedef __attribute__((ext_vector_type(8))) _Float16 f16x8;
typedef __attribute__((ext_vector_type(4))) _Float16 f16x4;
typedef __attribute__((ext_vector_type(4))) float    f32x4;

#define LOG2E 1.4426950408889634f
#define L2_10000_DIV32 0.41524101186092029f  /* log2(10000)/32 */

__device__ __forceinline__ float fin(float v) { return (v == v) ? v : 0.0f; }

__device__ __forceinline__ f16x8 cvt8(const float* p) {
  float4 a = *(const float4*)p;
  float4 b = *(const float4*)(p + 4);
  f16x8 h;
  h[0] = (f16)a.x; h[1] = (f16)a.y; h[2] = (f16)a.z; h[3] = (f16)a.w;
  h[4] = (f16)b.x; h[5] = (f16)b.y; h[6] = (f16)b.z; h[7] = (f16)b.w;
  return h;
}

// 16B-chunk XOR swizzle for [R][64] f16 tiles (stride 64, no pad).
__device__ __forceinline__ int swz64(int r, int c) {
  return r * 64 + ((((c >> 3) ^ (r & 7)) << 3) | (c & 7));
}

// global -> LDS direct DMA, 16B per lane.
#define GLD16(g, l)                                                        \
  __builtin_amdgcn_global_load_lds(                                        \
      (const __attribute__((address_space(1))) void*)(g),                  \
      (__attribute__((address_space(3))) void*)(l), 16, 0, 0)

// ---------------------------------------------------------------------------
// Kernel 0: fp32 -> f16 conversion of weights (and x) + RoPE cos/sin table.
// ---------------------------------------------------------------------------
__global__ void __launch_bounds__(256)
k_cvt3(const float* __restrict__ wq, const float* __restrict__ wo,
       const float* __restrict__ x,
       f16* __restrict__ wqh, f16* __restrict__ woh, f16* __restrict__ xh,
       float2* __restrict__ tab, int doX)
{
  const int NWQ = 3 * D_ * D_ / 4, NWO = D_ * D_ / 4, NX = B_ * S_ * D_ / 4;
  const int n = NWQ + NWO + (doX ? NX : 0);
  for (int i = blockIdx.x * 256 + threadIdx.x; i < n; i += gridDim.x * 256) {
    const float* src; f16* dst; int j;
    if (i < NWQ)            { src = wq; dst = wqh; j = i; }
    else if (i < NWQ + NWO) { src = wo; dst = woh; j = i - NWQ; }
    else                    { src = x;  dst = xh;  j = i - NWQ - NWO; }
    float4 v = ((const float4*)src)[j];
    f16x4 h = {(f16)v.x, (f16)v.y, (f16)v.z, (f16)v.w};
    ((f16x4*)dst)[j] = h;
  }
  for (int i = blockIdx.x * 256 + threadIdx.x; i < S_ * 32; i += gridDim.x * 256) {
    const int p = i >> 5, j = i & 31;
    const float th = exp2f(-(float)j * L2_10000_DIV32);
    float s, c;
    sincosf((float)p * th, &s, &c);
    tab[i] = make_float2(c, s);
  }
}

// ---------------------------------------------------------------------------
// Kernel 1 (r13): qkv = x @ w_qkv^T + RoPE epilogue.
// T3 minimum-2-phase restructure: DOUBLE-BUFFERED LDS; per K-step the stage
// of tile t+1 is ISSUED FIRST, then compute(t), then ONE __syncthreads()
// (its implicit vmcnt(0) drain lands AFTER ~400cy of MFMA+ds_read, hiding
// the HBM/L2 latency that the old issue->drain->compute order exposed).
// Barriers per tile: 2 -> 1. Compute reads use the nt-invariant swizzle
// identity (swz64(nt*16+ll,c) = nt*1024 + swz64(ll,c)).
// ---------------------------------------------------------------------------
template <bool XF16>
__global__ void __launch_bounds__(256)
k_qkv4(const float* __restrict__ xf, const f16* __restrict__ xh,
       const f16* __restrict__ wqh, const float2* __restrict__ tab,
       f16* __restrict__ Qb, f16* __restrict__ Kb, f16* __restrict__ Vt)
{
  __shared__ __align__(16) f16 As[2][128 * 64];   // 2 x 16 KB (dbuf)
  __shared__ __align__(16) f16 Bs[2][128 * 64];   // 2 x 16 KB
  const int t = threadIdx.x;
  const int w = t >> 6;
  const int lane = t & 63;
  const int ll = lane & 15;
  const int quad = lane >> 4;
  const int wm = w >> 1, wn = w & 1;
  const int row0 = blockIdx.y * 128;
  const int col0 = blockIdx.x * 128;

  const f32x4 fz = {0.f, 0.f, 0.f, 0.f};
  f32x4 acc[4][4];
#pragma unroll
  for (int i = 0; i < 4; ++i)
#pragma unroll
    for (int j = 0; j < 4; ++j) acc[i][j] = fz;

  // DMA geometry: wave w, issue i covers rows i*32 + w*8 + (lane>>3),
  // 16B chunk (lane&7); source chunk XOR-pre-swizzled.
  const int rO = lane >> 3;
  const int gc = (lane & 7) ^ rO;
  const f16* pA = xh  + (size_t)(row0 + w * 8 + rO) * D_ + gc * 8;
  const f16* pB = wqh + (size_t)(col0 + w * 8 + rO) * D_ + gc * 8;
  const int ldst = (w * 8) * 64;            // wave-uniform LDS dest base

  // Loop-invariant swizzled read offsets (compute side).
  const int raA0 = swz64(ll, quad * 8);
  const int raA1 = swz64(ll, 32 + quad * 8);

  // Fallback path (fp32 x): VGPR staging + converted, swizzled ds_write.
  const int ldr = t >> 3;
  const int ldk = (t & 7) * 8;
  const float* gaf = xf + (size_t)(row0 + ldr) * D_ + ldk;

  if (XF16) {
    // ---- prologue: stage tile 0 -> buf 0 ----
#pragma unroll
    for (int i = 0; i < 4; ++i) {
      GLD16(pA + (size_t)(i * 32) * D_, &As[0][i * 32 * 64 + ldst]);
      GLD16(pB + (size_t)(i * 32) * D_, &Bs[0][i * 32 * 64 + ldst]);
    }
    __syncthreads();
    pA += 64; pB += 64;

    for (int kt = 0; kt < 16; ++kt) {
      const int cur = kt & 1, nxt = cur ^ 1;
      if (kt < 15) {   // issue next-tile stage FIRST (latency hides under compute)
#pragma unroll
        for (int i = 0; i < 4; ++i) {
          GLD16(pA + (size_t)(i * 32) * D_, &As[nxt][i * 32 * 64 + ldst]);
          GLD16(pB + (size_t)(i * 32) * D_, &Bs[nxt][i * 32 * 64 + ldst]);
        }
        pA += 64; pB += 64;
      }
      const f16* Ac = &As[cur][0];
      const f16* Bc = &Bs[cur][0];
#pragma unroll
      for (int kk = 0; kk < 2; ++kk) {
        const int ro = kk ? raA1 : raA0;
        f16x8 a[4], b[4];
#pragma unroll
        for (int mt = 0; mt < 4; ++mt)
          a[mt] = *(const f16x8*)&Ac[(wm * 64 + mt * 16) * 64 + ro];
#pragma unroll
        for (int nt = 0; nt < 4; ++nt)
          b[nt] = *(const f16x8*)&Bc[(wn * 64 + nt * 16) * 64 + ro];
#pragma unroll
        for (int mt = 0; mt < 4; ++mt)
#pragma unroll
          for (int nt = 0; nt < 4; ++nt)
            acc[mt][nt] = __builtin_amdgcn_mfma_f32_16x16x32_f16(
                a[mt], b[nt], acc[mt][nt], 0, 0, 0);
      }
      __syncthreads();   // one barrier/tile; drains this iter's GLDs post-compute
    }
  } else {
    // Fallback: old 2-barrier structure on buf 0 (correctness path).
    for (int kt = 0; kt < D_; kt += 64) {
      f16x8 ra[4];
#pragma unroll
      for (int i = 0; i < 4; ++i)
        ra[i] = cvt8(gaf + (size_t)i * 32 * D_ + kt);
      __syncthreads();
#pragma unroll
      for (int i = 0; i < 4; ++i) {
        *(f16x8*)&As[0][swz64(i * 32 + ldr, ldk)] = ra[i];
        GLD16(pB + (size_t)(i * 32) * D_ + kt, &Bs[0][i * 32 * 64 + ldst]);
      }
      __syncthreads();
#pragma unroll
      for (int kk = 0; kk < 2; ++kk) {
        const int ro = kk ? raA1 : raA0;
        f16x8 a[4], b[4];
#pragma unroll
        for (int mt = 0; mt < 4; ++mt)
          a[mt] = *(const f16x8*)&As[0][(wm * 64 + mt * 16) * 64 + ro];
#pragma unroll
        for (int nt = 0; nt < 4; ++nt)
          b[nt] = *(const f16x8*)&Bs[0][(wn * 64 + nt * 16) * 64 + ro];
#pragma unroll
        for (int mt = 0; mt < 4; ++mt)
#pragma unroll
          for (int nt = 0; nt < 4; ++nt)
            acc[mt][nt] = __builtin_amdgcn_mfma_f32_16x16x32_f16(
                a[mt], b[nt], acc[mt][nt], 0, 0, 0);
      }
      __syncthreads();
    }
  }

  const int h3 = (col0 >> 6) + wn;
  if (h3 < 32) {
    f16* dst = (h3 < 16) ? Qb : Kb;
    const int h = (h3 < 16) ? h3 : h3 - 16;
#pragma unroll
    for (int mt = 0; mt < 4; ++mt) {
#pragma unroll
      for (int r = 0; r < 4; ++r) {
        const int row = row0 + wm * 64 + mt * 16 + quad * 4 + r;
        const int b = row >> 11;
        const int p = row & (S_ - 1);
        f16* base = dst + ((size_t)(b * H_ + h) * S_ + p) * HD_;
        const float2 cs0 = tab[p * 32 + ll];
        const float2 cs1 = tab[p * 32 + 16 + ll];
        {
          float x1 = acc[mt][0][r], x2 = acc[mt][2][r];
          base[ll]      = (f16)fin(x1 * cs0.x - x2 * cs0.y);
          base[ll + 32] = (f16)fin(x2 * cs0.x + x1 * cs0.y);
        }
        {
          float x1 = acc[mt][1][r], x2 = acc[mt][3][r];
          base[16 + ll]      = (f16)fin(x1 * cs1.x - x2 * cs1.y);
          base[16 + ll + 32] = (f16)fin(x2 * cs1.x + x1 * cs1.y);
        }
      }
    }
  } else {
    const int hv = h3 - 32;
#pragma unroll
    for (int mt = 0; mt < 4; ++mt)
#pragma unroll
      for (int nt = 0; nt < 4; ++nt)
#pragma unroll
        for (int r = 0; r < 4; ++r) {
          const int row = row0 + wm * 64 + mt * 16 + quad * 4 + r;
          const int b = row >> 11;
          const int p = row & (S_ - 1);
          const int dd = nt * 16 + ll;
          Vt[((size_t)(b * H_ + hv) * HD_ + dd) * S_ + p] = (f16)fin(acc[mt][nt][r]);
        }
  }
}

// ---------------------------------------------------------------------------
// k_attn7: causal flash attention (UNCHANGED from r12 — verified, fell out
// of the top-5). Loop-invariant LDS bases, x2 unroll, peeled diagonal.
// ---------------------------------------------------------------------------
__device__ __forceinline__ bool softmax_tile7(
    f32x4 sc[4], bool diag, int qloc, int quad,
    float& mrun, float& lrun, float& alpha, f16* const pst[4])
{
  if (diag) {
#pragma unroll
    for (int nt = 0; nt < 4; ++nt)
#pragma unroll
      for (int r = 0; r < 4; ++r)
        if ((nt * 16 + quad * 4 + r) > qloc) sc[nt][r] = -3.0e4f;
  }
  float pm = mrun;
#pragma unroll
  for (int nt = 0; nt < 4; ++nt)
#pragma unroll
    for (int r = 0; r < 4; ++r) pm = fmaxf(pm, sc[nt][r]);
  pm = fmaxf(pm, __shfl_xor(pm, 16));
  pm = fmaxf(pm, __shfl_xor(pm, 32));
  const bool resc = !__all(pm <= mrun + 8.0f);   // defer-max: P bounded by 2^8
  if (resc) { alpha = exp2f(mrun - pm); mrun = pm; }
  float ps = 0.f;
#pragma unroll
  for (int nt = 0; nt < 4; ++nt) {
    f16x4 pk;
#pragma unroll
    for (int r = 0; r < 4; ++r) {
      float p = exp2f(sc[nt][r] - mrun);
      ps += p;
      pk[r] = (f16)p;
    }
    *(f16x4*)pst[nt] = pk;
  }
  ps += __shfl_xor(ps, 16);
  ps += __shfl_xor(ps, 32);
  lrun = (resc ? lrun * alpha : lrun) + ps;
  return resc;
}

__device__ __forceinline__ void write_o7(
    f32x4 acco[4], float lrun, f16* const pst[4],
    const f16* pb0, const f16* pb1,
    int ll, int quad, int w, int qt, size_t bh, f16* Ob)
{
  const float inv = 1.0f / fmaxf(lrun, 1e-30f);
#pragma unroll
  for (int dg = 0; dg < 4; ++dg) {
    f16x4 ov;
#pragma unroll
    for (int r = 0; r < 4; ++r) ov[r] = (f16)fin(acco[dg][r] * inv);
    *(f16x4*)pst[dg] = ov;
  }
  const size_t row = bh * S_ + qt * 64 + w * 16 + ll;
  f16x8 o0 = *(const f16x8*)pb0;
  f16x8 o1 = *(const f16x8*)pb1;
  *(f16x8*)&Ob[row * HD_ + quad * 8]      = o0;
  *(f16x8*)&Ob[row * HD_ + 32 + quad * 8] = o1;
}

#define ABODY(KB0, KB1, VB0, VB1, WKA, WKB, WVA, WVB, PRE, DIAG)           \
  do {                                                                     \
    f16x8 nk0, nk1, nv0, nv1;                                              \
    if (PRE) {                                                             \
      nk0 = *(const f16x8*)pK; nk1 = *(const f16x8*)(pK + 8);              \
    }                                                                      \
    f16x8 ak[2][4];                                                        \
    _Pragma("unroll")                                                      \
    for (int nt = 0; nt < 4; ++nt) {                                       \
      ak[0][nt] = *(const f16x8*)(KB0 + nt * 1024);                        \
      ak[1][nt] = *(const f16x8*)(KB1 + nt * 1024);                        \
    }                                                                      \
    f32x4 s[4] = {fz, fz, fz, fz};                                         \
    __builtin_amdgcn_s_setprio(1);                                         \
    _Pragma("unroll")                                                      \
    for (int k2 = 0; k2 < 2; ++k2)                                         \
      _Pragma("unroll")                                                    \
      for (int nt = 0; nt < 4; ++nt)                                       \
        s[nt] = __builtin_amdgcn_mfma_f32_16x16x32_f16(                    \
            ak[k2][nt], bq[k2], s[nt], 0, 0, 0);                           \
    __builtin_amdgcn_s_setprio(0);                                         \
    if (PRE) {                                                             \
      nv0 = *(const f16x8*)pV; nv1 = *(const f16x8*)(pV + 8);              \
      pK += 64 * HD_; pV += 64;                                            \
    }                                                                      \
    float alpha;                                                           \
    const bool resc = softmax_tile7(s, DIAG, qloc, quad, m, l, alpha, pst);\
    if (resc) {                                                            \
      _Pragma("unroll")                                                    \
      for (int dg = 0; dg < 4; ++dg)                                       \
        _Pragma("unroll")                                                  \
        for (int r = 0; r < 4; ++r) acco[dg][r] *= alpha;                  \
    }                                                                      \
    f16x8 av[2][4];                                                        \
    _Pragma("unroll")                                                      \
    for (int dg = 0; dg < 4; ++dg) {                                       \
      av[0][dg] = *(const f16x8*)(VB0 + dg * 1024);                        \
      av[1][dg] = *(const f16x8*)(VB1 + dg * 1024);                        \
    }                                                                      \
    f16x8 bp0 = *(const f16x8*)pb0;                                        \
    f16x8 bp1 = *(const f16x8*)pb1;                                        \
    __builtin_amdgcn_s_setprio(1);                                         \
    _Pragma("unroll")                                                      \
    for (int dg = 0; dg < 4; ++dg)                                         \
      acco[dg] = __builtin_amdgcn_mfma_f32_16x16x32_f16(                   \
          av[0][dg], bp0, acco[dg], 0, 0, 0);                              \
    _Pragma("unroll")                                                      \
    for (int dg = 0; dg < 4; ++dg)                                         \
      acco[dg] = __builtin_amdgcn_mfma_f32_16x16x32_f16(                   \
          av[1][dg], bp1, acco[dg], 0, 0, 0);                              \
    __builtin_amdgcn_s_setprio(0);                                         \
    if (PRE) {                                                             \
      *(f16x8*)WKA = nk0; *(f16x8*)WKB = nk1;                              \
      *(f16x8*)WVA = nv0; *(f16x8*)WVB = nv1;                              \
    }                                                                      \
    __syncthreads();                                                       \
  } while (0)

#define ABODY_B0(PRE, DIAG) \
  ABODY(kb00, kb01, vb00, vb01, wk1a, wk1b, wv1a, wv1b, PRE, DIAG)
#define ABODY_B1(PRE, DIAG) \
  ABODY(kb10, kb11, vb10, vb11, wk0a, wk0b, wv0a, wv0b, PRE, DIAG)

__global__ void __launch_bounds__(256, 4)
k_attn7(const f16* Qb, const f16* __restrict__ Kb,
        const f16* __restrict__ Vt, f16* Ob)
{
  __shared__ __align__(16) f16 Ks[2][64 * 64];
  __shared__ __align__(16) f16 Vs[2][64 * 64];
  __shared__ __align__(16) f16 Ps[4][16 * 64];

  const int t = threadIdx.x;
  const int w = t >> 6;
  const int lane = t & 63;
  const int ll = lane & 15;
  const int quad = lane >> 4;
  const int bx = blockIdx.x;
  const int base = (bx & 1) ? 31 - (bx >> 1) : (bx >> 1);
  const int qt = ((int)blockIdx.y < 8) ? base : 31 - base;
  const int h = blockIdx.y;
  const int b = blockIdx.z;
  const size_t bh = (size_t)b * H_ + h;
  const f16* Qg = Qb + bh * S_ * HD_;
  const f16* Kg = Kb + bh * S_ * HD_;
  const f16* Vg = Vt + bh * HD_ * S_;

  f16x8 bq[2];
  {
    const f16 hsc = (f16)(0.125f * LOG2E);
#pragma unroll
    for (int k2 = 0; k2 < 2; ++k2) {
      bq[k2] = *(const f16x8*)(Qg + (size_t)(qt * 64 + w * 16 + ll) * HD_ + k2 * 32 + quad * 8);
#pragma unroll
      for (int e = 0; e < 8; ++e) bq[k2][e] *= hsc;
    }
  }

  f16* Pt = &Ps[w][0];
  const f16* kb00 = &Ks[0][swz64(ll, quad * 8)];
  const f16* kb01 = &Ks[0][swz64(ll, 32 + quad * 8)];
  const f16* kb10 = &Ks[1][swz64(ll, quad * 8)];
  const f16* kb11 = &Ks[1][swz64(ll, 32 + quad * 8)];
  const f16* vb00 = &Vs[0][swz64(ll, quad * 8)];
  const f16* vb01 = &Vs[0][swz64(ll, 32 + quad * 8)];
  const f16* vb10 = &Vs[1][swz64(ll, quad * 8)];
  const f16* vb11 = &Vs[1][swz64(ll, 32 + quad * 8)];
  const f16* pb0  = &Pt[swz64(ll, quad * 8)];
  const f16* pb1  = &Pt[swz64(ll, 32 + quad * 8)];
  f16* pst[4] = { &Pt[swz64(ll, 0 * 16 + quad * 4)],
                  &Pt[swz64(ll, 1 * 16 + quad * 4)],
                  &Pt[swz64(ll, 2 * 16 + quad * 4)],
                  &Pt[swz64(ll, 3 * 16 + quad * 4)] };
  const int sr = t >> 2;
  const int scc = (t & 3) * 16;
  f16* wk0a = &Ks[0][swz64(sr, scc)];
  f16* wk0b = &Ks[0][swz64(sr, scc + 8)];
  f16* wk1a = &Ks[1][swz64(sr, scc)];
  f16* wk1b = &Ks[1][swz64(sr, scc + 8)];
  f16* wv0a = &Vs[0][swz64(sr, scc)];
  f16* wv0b = &Vs[0][swz64(sr, scc + 8)];
  f16* wv1a = &Vs[1][swz64(sr, scc)];
  f16* wv1b = &Vs[1][swz64(sr, scc + 8)];

  {
    f16x8 a0 = *(const f16x8*)(Kg + (size_t)sr * HD_ + scc);
    f16x8 a1 = *(const f16x8*)(Kg + (size_t)sr * HD_ + scc + 8);
    f16x8 b0 = *(const f16x8*)(Vg + (size_t)sr * S_ + scc);
    f16x8 b1 = *(const f16x8*)(Vg + (size_t)sr * S_ + scc + 8);
    *(f16x8*)wk0a = a0;
    *(f16x8*)wk0b = a1;
    *(f16x8*)wv0a = b0;
    *(f16x8*)wv0b = b1;
  }
  __syncthreads();

  const f16* pK = Kg + (size_t)(64 + sr) * HD_ + scc;
  const f16* pV = Vg + (size_t)sr * S_ + 64 + scc;

  const f32x4 fz = {0.f, 0.f, 0.f, 0.f};
  f32x4 acco[4] = {fz, fz, fz, fz};
  float m = -3.0e4f, l = 0.f;
  const int qloc = w * 16 + ll;

  int j = 0;
  while (j + 1 < qt) {
    ABODY_B0(true, false);
    ABODY_B1(true, false);
    j += 2;
  }
  if (j < qt) {
    ABODY_B0(true, false);
    ++j;
    ABODY_B1(false, true);
  } else {
    ABODY_B0(false, true);
  }

  write_o7(acco, l, pst, pb0, pb1, ll, quad, w, qt, bh, Ob);
}

// ---------------------------------------------------------------------------
// Kernel 3 (r13): out = O @ w_out^T + b_out. Same T3 2-phase restructure:
// dbuf LDS (48 KB), stage t+1 issued before compute(t), 1 barrier/tile.
// ---------------------------------------------------------------------------
__global__ void __launch_bounds__(256)
k_out4(const f16* __restrict__ Ob, const f16* __restrict__ Wh,
       const float* __restrict__ bias, float* __restrict__ out)
{
  __shared__ __align__(16) f16 As[2][64 * 64];    // 2 x 8 KB
  __shared__ __align__(16) f16 Bs[2][128 * 64];   // 2 x 16 KB
  const int t = threadIdx.x;
  const int w = t >> 6;
  const int lane = t & 63;
  const int ll = lane & 15;
  const int quad = lane >> 4;
  const int wm = w >> 1, wn = w & 1;
  const int row0 = blockIdx.y * 64;
  const int col0 = blockIdx.x * 128;
  const int bb = row0 >> 11;
  const int s0 = row0 & (S_ - 1);

  const f32x4 fz = {0.f, 0.f, 0.f, 0.f};
  f32x4 acc[2][4];
#pragma unroll
  for (int i = 0; i < 2; ++i)
#pragma unroll
    for (int j = 0; j < 4; ++j) acc[i][j] = fz;

  const int rO = lane >> 3;
  const int gc = (lane & 7) ^ rO;
  const int ldst = (w * 8) * 64;
  const f16* pB = Wh + (size_t)(col0 + w * 8 + rO) * D_ + gc * 8;
  const f16* pA = Ob + (((size_t)(bb * H_)) * S_ + s0 + w * 8 + rO) * HD_ + gc * 8;

  const int raA0 = swz64(ll, quad * 8);
  const int raA1 = swz64(ll, 32 + quad * 8);

  // prologue: stage kt=0 -> buf 0
#pragma unroll
  for (int i = 0; i < 2; ++i)
    GLD16(pA + (size_t)(i * 32) * HD_, &As[0][i * 32 * 64 + ldst]);
#pragma unroll
  for (int i = 0; i < 4; ++i)
    GLD16(pB + (size_t)(i * 32) * D_, &Bs[0][i * 32 * 64 + ldst]);
  __syncthreads();
  pA += (size_t)S_ * HD_;   // next head
  pB += 64;

  for (int kt = 0; kt < 16; ++kt) {
    const int cur = kt & 1, nxt = cur ^ 1;
    if (kt < 15) {
#pragma unroll
      for (int i = 0; i < 2; ++i)
        GLD16(pA + (size_t)(i * 32) * HD_, &As[nxt][i * 32 * 64 + ldst]);
#pragma unroll
      for (int i = 0; i < 4; ++i)
        GLD16(pB + (size_t)(i * 32) * D_, &Bs[nxt][i * 32 * 64 + ldst]);
      pA += (size_t)S_ * HD_;
      pB += 64;
    }
    const f16* Ac = &As[cur][0];
    const f16* Bc = &Bs[cur][0];
#pragma unroll
    for (int kk = 0; kk < 2; ++kk) {
      const int ro = kk ? raA1 : raA0;
      f16x8 a[2], b[4];
#pragma unroll
      for (int mt = 0; mt < 2; ++mt)
        a[mt] = *(const f16x8*)&Ac[(wm * 32 + mt * 16) * 64 + ro];
#pragma unroll
      for (int nt = 0; nt < 4; ++nt)
        b[nt] = *(const f16x8*)&Bc[(wn * 64 + nt * 16) * 64 + ro];
#pragma unroll
      for (int mt = 0; mt < 2; ++mt)
#pragma unroll
        for (int nt = 0; nt < 4; ++nt)
          acc[mt][nt] = __builtin_amdgcn_mfma_f32_16x16x32_f16(
              a[mt], b[nt], acc[mt][nt], 0, 0, 0);
    }
    __syncthreads();
  }

#pragma unroll
  for (int mt = 0; mt < 2; ++mt)
#pragma unroll
    for (int r = 0; r < 4; ++r) {
      const int row = row0 + wm * 32 + mt * 16 + quad * 4 + r;
#pragma unroll
      for (int nt = 0; nt < 4; ++nt) {
        const int col = col0 + wn * 64 + nt * 16 + ll;
        out[(size_t)row * D_ + col] = fin(acc[mt][nt][r] + bias[col]);
      }
    }
}

// ---------------------------------------------------------------------------
extern "C" void kernel_launch(void* const* d_in, const int* in_sizes, int n_in,
                              void* d_out, int out_size, void* d_ws, size_t ws_size,
                              hipStream_t stream) {
  const float* x    = (const float*)d_in[0];
  const float* wqkv = (const float*)d_in[1];
  const float* wout = (const float*)d_in[2];
  const float* bout = (const float*)d_in[3];
  float* out = (float*)d_out;

  // ws: wqkvh 6M | Qb/O 8M | Kb 8M | Vt 8M | woh 2M | xh 8M (if big ws)
  char* ws = (char*)d_ws;
  f16* wqh = (f16*)(ws);
  f16* Qb  = (f16*)(ws + 6291456);
  f16* Kb  = (f16*)(ws + 14680064);
  f16* Vt  = (f16*)(ws + 23068672);
  f16* woh = (f16*)(ws + 31457280);
  const bool bigws = ws_size >= (size_t)41943040;
  f16* xh  = (f16*)(ws + 33554432);

  // RoPE table lives in d_out scratch (overwritten by k_out4 last).
  float2* tab = (float2*)((char*)d_out + 9437184);

  k_cvt3<<<2048, 256, 0, stream>>>(wqkv, wout, x, wqh, woh, xh, tab, bigws ? 1 : 0);
  if (bigws)
    k_qkv4<true><<<dim3(3 * D_ / 128, (B_ * S_) / 128), 256, 0, stream>>>(
        x, xh, wqh, tab, Qb, Kb, Vt);
  else
    k_qkv4<false><<<dim3(3 * D_ / 128, (B_ * S_) / 128), 256, 0, stream>>>(
        x, xh, wqh, tab, Qb, Kb, Vt);
  k_attn7<<<dim3(32, H_, B_), 256, 0, stream>>>(Qb, Kb, Vt, Qb /* O in place */);
  k_out4<<<dim3(D_ / 128, (B_ * S_) / 64), 256, 0, stream>>>(
      Qb, woh, bout, out);
}

// Round 7
// 180.831 us; speedup vs baseline: 1.1163x; 1.1163x over previous
//
#include <hip/hip_runtime.h>
#include <hip/hip_fp16.h>
#include <math.h>

// Problem: B=2, S=2048, D=1024, H=16, HD=64, causal attention + RoPE.
// ALL inputs fp32 (reference dtypes), output fp32.
#define B_  2
#define S_  2048
#define D_  1024
#define H_  16
#define HD_ 64

typedef _Float16  f16;
typedef __attribute__((ext_vector_type(8))) _Float16 f16x8;
typedef __attribute__((ext_vector_type(4))) _Float16 f16x4;
typedef __attribute__((ext_vector_type(4))) float    f32x4;

#define LOG2E 1.4426950408889634f
#define L2_10000_DIV32 0.41524101186092029f  /* log2(10000)/32 */

__device__ __forceinline__ float fin(float v) { return (v == v) ? v : 0.0f; }

__device__ __forceinline__ f16x8 cvt8(const float* p) {
  float4 a = *(const float4*)p;
  float4 b = *(const float4*)(p + 4);
  f16x8 h;
  h[0] = (f16)a.x; h[1] = (f16)a.y; h[2] = (f16)a.z; h[3] = (f16)a.w;
  h[4] = (f16)b.x; h[5] = (f16)b.y; h[6] = (f16)b.z; h[7] = (f16)b.w;
  return h;
}

// 16B-chunk XOR swizzle for [R][64] f16 tiles (stride 64, no pad).
__device__ __forceinline__ int swz64(int r, int c) {
  return r * 64 + ((((c >> 3) ^ (r & 7)) << 3) | (c & 7));
}

// global -> LDS direct DMA, 16B per lane.
#define GLD16(g, l)                                                        \
  __builtin_amdgcn_global_load_lds(                                        \
      (const __attribute__((address_space(1))) void*)(g),                  \
      (__attribute__((address_space(3))) void*)(l), 16, 0, 0)

// ---------------------------------------------------------------------------
// Kernel 0: fp32 -> f16 conversion of weights (and x) + RoPE cos/sin table.
// ---------------------------------------------------------------------------
__global__ void __launch_bounds__(256)
k_cvt3(const float* __restrict__ wq, const float* __restrict__ wo,
       const float* __restrict__ x,
       f16* __restrict__ wqh, f16* __restrict__ woh, f16* __restrict__ xh,
       float2* __restrict__ tab, int doX)
{
  const int NWQ = 3 * D_ * D_ / 4, NWO = D_ * D_ / 4, NX = B_ * S_ * D_ / 4;
  const int n = NWQ + NWO + (doX ? NX : 0);
  for (int i = blockIdx.x * 256 + threadIdx.x; i < n; i += gridDim.x * 256) {
    const float* src; f16* dst; int j;
    if (i < NWQ)            { src = wq; dst = wqh; j = i; }
    else if (i < NWQ + NWO) { src = wo; dst = woh; j = i - NWQ; }
    else                    { src = x;  dst = xh;  j = i - NWQ - NWO; }
    float4 v = ((const float4*)src)[j];
    f16x4 h = {(f16)v.x, (f16)v.y, (f16)v.z, (f16)v.w};
    ((f16x4*)dst)[j] = h;
  }
  for (int i = blockIdx.x * 256 + threadIdx.x; i < S_ * 32; i += gridDim.x * 256) {
    const int p = i >> 5, j = i & 31;
    const float th = exp2f(-(float)j * L2_10000_DIV32);
    float s, c;
    sincosf((float)p * th, &s, &c);
    tab[i] = make_float2(c, s);
  }
}

// ---------------------------------------------------------------------------
// Kernel 1 (r14): qkv = x @ w_qkv^T + RoPE epilogue. Structure = r11
// (verified 55us: GLD16 staging, 2-barrier, 32KB LDS, table RoPE) + T1
// XCD-AWARE BLOCK SWIZZLE: round-robin dispatch puts the 24 blocks sharing
// an x row-panel on 8 different XCDs (FETCH 43MB vs 14MB ideal, staging
// loads pay L3/HBM latency). Remap so XCD c gets work-ids [96c, 96c+96)
// = 4 complete row-panels x 24 col-panels: x-panels L2-hit for 23/24
// sharers, W step-slices for 3/4. Bijective (768 % 8 == 0).
// ---------------------------------------------------------------------------
template <bool XF16>
__global__ void __launch_bounds__(256)
k_qkv3(const float* __restrict__ xf, const f16* __restrict__ xh,
       const f16* __restrict__ wqh, const float2* __restrict__ tab,
       f16* __restrict__ Qb, f16* __restrict__ Kb, f16* __restrict__ Vt)
{
  __shared__ __align__(16) f16 As[128 * 64];   // 16 KB, linear (DMA dest)
  __shared__ __align__(16) f16 Bs[128 * 64];   // 16 KB
  const int t = threadIdx.x;
  const int w = t >> 6;
  const int lane = t & 63;
  const int ll = lane & 15;
  const int quad = lane >> 4;
  const int wm = w >> 1, wn = w & 1;

  // T1 XCD swizzle: flat%8 = XCD under round-robin; give each XCD a
  // contiguous work chunk (row-major, cols fastest).
  const int flat  = blockIdx.y * 24 + blockIdx.x;      // 0..767
  const int newid = (flat & 7) * 96 + (flat >> 3);
  const int row0 = (newid / 24) * 128;
  const int col0 = (newid % 24) * 128;

  const f32x4 fz = {0.f, 0.f, 0.f, 0.f};
  f32x4 acc[4][4];
#pragma unroll
  for (int i = 0; i < 4; ++i)
#pragma unroll
    for (int j = 0; j < 4; ++j) acc[i][j] = fz;

  const int rO = lane >> 3;              // 0..7
  const int gc = (lane & 7) ^ rO;        // swizzled chunk (row&7 == rO here)
  const f16* gah2 = xh  + (size_t)(row0 + w * 8 + rO) * D_ + gc * 8;
  const f16* gb2  = wqh + (size_t)(col0 + w * 8 + rO) * D_ + gc * 8;

  const int ldr = t >> 3;
  const int ldk = (t & 7) * 8;
  const float* gaf = xf + (size_t)(row0 + ldr) * D_ + ldk;

  for (int kt = 0; kt < D_; kt += 64) {
    f16x8 ra[4];
    if (!XF16) {
#pragma unroll
      for (int i = 0; i < 4; ++i)
        ra[i] = cvt8(gaf + (size_t)i * 32 * D_ + kt);
    }
    __syncthreads();   // prior compute done reading LDS
    if (XF16) {
#pragma unroll
      for (int i = 0; i < 4; ++i) {
        GLD16(gah2 + (size_t)(i * 32) * D_ + kt, &As[(i * 32 + w * 8) * 64]);
        GLD16(gb2  + (size_t)(i * 32) * D_ + kt, &Bs[(i * 32 + w * 8) * 64]);
      }
    } else {
#pragma unroll
      for (int i = 0; i < 4; ++i) {
        *(f16x8*)&As[swz64(i * 32 + ldr, ldk)] = ra[i];
        GLD16(gb2 + (size_t)(i * 32) * D_ + kt, &Bs[(i * 32 + w * 8) * 64]);
      }
    }
    __syncthreads();   // drains vmcnt(0): DMA'd tile visible
#pragma unroll
    for (int kk = 0; kk < 64; kk += 32) {
      f16x8 a[4], b[4];
#pragma unroll
      for (int mt = 0; mt < 4; ++mt)
        a[mt] = *(const f16x8*)&As[swz64(wm * 64 + mt * 16 + ll, kk + quad * 8)];
#pragma unroll
      for (int nt = 0; nt < 4; ++nt)
        b[nt] = *(const f16x8*)&Bs[swz64(wn * 64 + nt * 16 + ll, kk + quad * 8)];
#pragma unroll
      for (int mt = 0; mt < 4; ++mt)
#pragma unroll
        for (int nt = 0; nt < 4; ++nt)
          acc[mt][nt] = __builtin_amdgcn_mfma_f32_16x16x32_f16(
              a[mt], b[nt], acc[mt][nt], 0, 0, 0);
    }
  }

  const int h3 = (col0 >> 6) + wn;
  if (h3 < 32) {
    f16* dst = (h3 < 16) ? Qb : Kb;
    const int h = (h3 < 16) ? h3 : h3 - 16;
#pragma unroll
    for (int mt = 0; mt < 4; ++mt) {
#pragma unroll
      for (int r = 0; r < 4; ++r) {
        const int row = row0 + wm * 64 + mt * 16 + quad * 4 + r;
        const int b = row >> 11;
        const int p = row & (S_ - 1);
        f16* base = dst + ((size_t)(b * H_ + h) * S_ + p) * HD_;
        const float2 cs0 = tab[p * 32 + ll];
        const float2 cs1 = tab[p * 32 + 16 + ll];
        {
          float x1 = acc[mt][0][r], x2 = acc[mt][2][r];
          base[ll]      = (f16)fin(x1 * cs0.x - x2 * cs0.y);
          base[ll + 32] = (f16)fin(x2 * cs0.x + x1 * cs0.y);
        }
        {
          float x1 = acc[mt][1][r], x2 = acc[mt][3][r];
          base[16 + ll]      = (f16)fin(x1 * cs1.x - x2 * cs1.y);
          base[16 + ll + 32] = (f16)fin(x2 * cs1.x + x1 * cs1.y);
        }
      }
    }
  } else {
    const int hv = h3 - 32;
#pragma unroll
    for (int mt = 0; mt < 4; ++mt)
#pragma unroll
      for (int nt = 0; nt < 4; ++nt)
#pragma unroll
        for (int r = 0; r < 4; ++r) {
          const int row = row0 + wm * 64 + mt * 16 + quad * 4 + r;
          const int b = row >> 11;
          const int p = row & (S_ - 1);
          const int dd = nt * 16 + ll;
          Vt[((size_t)(b * H_ + hv) * HD_ + dd) * S_ + p] = (f16)fin(acc[mt][nt][r]);
        }
  }
}

// ---------------------------------------------------------------------------
// k_attn7: causal flash attention (UNCHANGED — verified r12/r13).
// Loop-invariant LDS bases, x2 unroll, peeled diagonal, setprio.
// ---------------------------------------------------------------------------
__device__ __forceinline__ bool softmax_tile7(
    f32x4 sc[4], bool diag, int qloc, int quad,
    float& mrun, float& lrun, float& alpha, f16* const pst[4])
{
  if (diag) {
#pragma unroll
    for (int nt = 0; nt < 4; ++nt)
#pragma unroll
      for (int r = 0; r < 4; ++r)
        if ((nt * 16 + quad * 4 + r) > qloc) sc[nt][r] = -3.0e4f;
  }
  float pm = mrun;
#pragma unroll
  for (int nt = 0; nt < 4; ++nt)
#pragma unroll
    for (int r = 0; r < 4; ++r) pm = fmaxf(pm, sc[nt][r]);
  pm = fmaxf(pm, __shfl_xor(pm, 16));
  pm = fmaxf(pm, __shfl_xor(pm, 32));
  const bool resc = !__all(pm <= mrun + 8.0f);   // defer-max: P bounded by 2^8
  if (resc) { alpha = exp2f(mrun - pm); mrun = pm; }
  float ps = 0.f;
#pragma unroll
  for (int nt = 0; nt < 4; ++nt) {
    f16x4 pk;
#pragma unroll
    for (int r = 0; r < 4; ++r) {
      float p = exp2f(sc[nt][r] - mrun);
      ps += p;
      pk[r] = (f16)p;
    }
    *(f16x4*)pst[nt] = pk;
  }
  ps += __shfl_xor(ps, 16);
  ps += __shfl_xor(ps, 32);
  lrun = (resc ? lrun * alpha : lrun) + ps;
  return resc;
}

__device__ __forceinline__ void write_o7(
    f32x4 acco[4], float lrun, f16* const pst[4],
    const f16* pb0, const f16* pb1,
    int ll, int quad, int w, int qt, size_t bh, f16* Ob)
{
  const float inv = 1.0f / fmaxf(lrun, 1e-30f);
#pragma unroll
  for (int dg = 0; dg < 4; ++dg) {
    f16x4 ov;
#pragma unroll
    for (int r = 0; r < 4; ++r) ov[r] = (f16)fin(acco[dg][r] * inv);
    *(f16x4*)pst[dg] = ov;
  }
  const size_t row = bh * S_ + qt * 64 + w * 16 + ll;
  f16x8 o0 = *(const f16x8*)pb0;
  f16x8 o1 = *(const f16x8*)pb1;
  *(f16x8*)&Ob[row * HD_ + quad * 8]      = o0;
  *(f16x8*)&Ob[row * HD_ + 32 + quad * 8] = o1;
}

#define ABODY(KB0, KB1, VB0, VB1, WKA, WKB, WVA, WVB, PRE, DIAG)           \
  do {                                                                     \
    f16x8 nk0, nk1, nv0, nv1;                                              \
    if (PRE) {                                                             \
      nk0 = *(const f16x8*)pK; nk1 = *(const f16x8*)(pK + 8);              \
    }                                                                      \
    f16x8 ak[2][4];                                                        \
    _Pragma("unroll")                                                      \
    for (int nt = 0; nt < 4; ++nt) {                                       \
      ak[0][nt] = *(const f16x8*)(KB0 + nt * 1024);                        \
      ak[1][nt] = *(const f16x8*)(KB1 + nt * 1024);                        \
    }                                                                      \
    f32x4 s[4] = {fz, fz, fz, fz};                                         \
    __builtin_amdgcn_s_setprio(1);                                         \
    _Pragma("unroll")                                                      \
    for (int k2 = 0; k2 < 2; ++k2)                                         \
      _Pragma("unroll")                                                    \
      for (int nt = 0; nt < 4; ++nt)                                       \
        s[nt] = __builtin_amdgcn_mfma_f32_16x16x32_f16(                    \
            ak[k2][nt], bq[k2], s[nt], 0, 0, 0);                           \
    __builtin_amdgcn_s_setprio(0);                                         \
    if (PRE) {                                                             \
      nv0 = *(const f16x8*)pV; nv1 = *(const f16x8*)(pV + 8);              \
      pK += 64 * HD_; pV += 64;                                            \
    }                                                                      \
    float alpha;                                                           \
    const bool resc = softmax_tile7(s, DIAG, qloc, quad, m, l, alpha, pst);\
    if (resc) {                                                            \
      _Pragma("unroll")                                                    \
      for (int dg = 0; dg < 4; ++dg)                                       \
        _Pragma("unroll")                                                  \
        for (int r = 0; r < 4; ++r) acco[dg][r] *= alpha;                  \
    }                                                                      \
    f16x8 av[2][4];                                                        \
    _Pragma("unroll")                                                      \
    for (int dg = 0; dg < 4; ++dg) {                                       \
      av[0][dg] = *(const f16x8*)(VB0 + dg * 1024);                        \
      av[1][dg] = *(const f16x8*)(VB1 + dg * 1024);                        \
    }                                                                      \
    f16x8 bp0 = *(const f16x8*)pb0;                                        \
    f16x8 bp1 = *(const f16x8*)pb1;                                        \
    __builtin_amdgcn_s_setprio(1);                                         \
    _Pragma("unroll")                                                      \
    for (int dg = 0; dg < 4; ++dg)                                         \
      acco[dg] = __builtin_amdgcn_mfma_f32_16x16x32_f16(                   \
          av[0][dg], bp0, acco[dg], 0, 0, 0);                              \
    _Pragma("unroll")                                                      \
    for (int dg = 0; dg < 4; ++dg)                                         \
      acco[dg] = __builtin_amdgcn_mfma_f32_16x16x32_f16(                   \
          av[1][dg], bp1, acco[dg], 0, 0, 0);                              \
    __builtin_amdgcn_s_setprio(0);                                         \
    if (PRE) {                                                             \
      *(f16x8*)WKA = nk0; *(f16x8*)WKB = nk1;                              \
      *(f16x8*)WVA = nv0; *(f16x8*)WVB = nv1;                              \
    }                                                                      \
    __syncthreads();                                                       \
  } while (0)

#define ABODY_B0(PRE, DIAG) \
  ABODY(kb00, kb01, vb00, vb01, wk1a, wk1b, wv1a, wv1b, PRE, DIAG)
#define ABODY_B1(PRE, DIAG) \
  ABODY(kb10, kb11, vb10, vb11, wk0a, wk0b, wv0a, wv0b, PRE, DIAG)

__global__ void __launch_bounds__(256, 4)
k_attn7(const f16* Qb, const f16* __restrict__ Kb,
        const f16* __restrict__ Vt, f16* Ob)
{
  __shared__ __align__(16) f16 Ks[2][64 * 64];
  __shared__ __align__(16) f16 Vs[2][64 * 64];
  __shared__ __align__(16) f16 Ps[4][16 * 64];

  const int t = threadIdx.x;
  const int w = t >> 6;
  const int lane = t & 63;
  const int ll = lane & 15;
  const int quad = lane >> 4;
  const int bx = blockIdx.x;
  const int base = (bx & 1) ? 31 - (bx >> 1) : (bx >> 1);
  const int qt = ((int)blockIdx.y < 8) ? base : 31 - base;
  const int h = blockIdx.y;
  const int b = blockIdx.z;
  const size_t bh = (size_t)b * H_ + h;
  const f16* Qg = Qb + bh * S_ * HD_;
  const f16* Kg = Kb + bh * S_ * HD_;
  const f16* Vg = Vt + bh * HD_ * S_;

  f16x8 bq[2];
  {
    const f16 hsc = (f16)(0.125f * LOG2E);
#pragma unroll
    for (int k2 = 0; k2 < 2; ++k2) {
      bq[k2] = *(const f16x8*)(Qg + (size_t)(qt * 64 + w * 16 + ll) * HD_ + k2 * 32 + quad * 8);
#pragma unroll
      for (int e = 0; e < 8; ++e) bq[k2][e] *= hsc;
    }
  }

  f16* Pt = &Ps[w][0];
  const f16* kb00 = &Ks[0][swz64(ll, quad * 8)];
  const f16* kb01 = &Ks[0][swz64(ll, 32 + quad * 8)];
  const f16* kb10 = &Ks[1][swz64(ll, quad * 8)];
  const f16* kb11 = &Ks[1][swz64(ll, 32 + quad * 8)];
  const f16* vb00 = &Vs[0][swz64(ll, quad * 8)];
  const f16* vb01 = &Vs[0][swz64(ll, 32 + quad * 8)];
  const f16* vb10 = &Vs[1][swz64(ll, quad * 8)];
  const f16* vb11 = &Vs[1][swz64(ll, 32 + quad * 8)];
  const f16* pb0  = &Pt[swz64(ll, quad * 8)];
  const f16* pb1  = &Pt[swz64(ll, 32 + quad * 8)];
  f16* pst[4] = { &Pt[swz64(ll, 0 * 16 + quad * 4)],
                  &Pt[swz64(ll, 1 * 16 + quad * 4)],
                  &Pt[swz64(ll, 2 * 16 + quad * 4)],
                  &Pt[swz64(ll, 3 * 16 + quad * 4)] };
  const int sr = t >> 2;
  const int scc = (t & 3) * 16;
  f16* wk0a = &Ks[0][swz64(sr, scc)];
  f16* wk0b = &Ks[0][swz64(sr, scc + 8)];
  f16* wk1a = &Ks[1][swz64(sr, scc)];
  f16* wk1b = &Ks[1][swz64(sr, scc + 8)];
  f16* wv0a = &Vs[0][swz64(sr, scc)];
  f16* wv0b = &Vs[0][swz64(sr, scc + 8)];
  f16* wv1a = &Vs[1][swz64(sr, scc)];
  f16* wv1b = &Vs[1][swz64(sr, scc + 8)];

  {
    f16x8 a0 = *(const f16x8*)(Kg + (size_t)sr * HD_ + scc);
    f16x8 a1 = *(const f16x8*)(Kg + (size_t)sr * HD_ + scc + 8);
    f16x8 b0 = *(const f16x8*)(Vg + (size_t)sr * S_ + scc);
    f16x8 b1 = *(const f16x8*)(Vg + (size_t)sr * S_ + scc + 8);
    *(f16x8*)wk0a = a0;
    *(f16x8*)wk0b = a1;
    *(f16x8*)wv0a = b0;
    *(f16x8*)wv0b = b1;
  }
  __syncthreads();

  const f16* pK = Kg + (size_t)(64 + sr) * HD_ + scc;
  const f16* pV = Vg + (size_t)sr * S_ + 64 + scc;

  const f32x4 fz = {0.f, 0.f, 0.f, 0.f};
  f32x4 acco[4] = {fz, fz, fz, fz};
  float m = -3.0e4f, l = 0.f;
  const int qloc = w * 16 + ll;

  int j = 0;
  while (j + 1 < qt) {
    ABODY_B0(true, false);
    ABODY_B1(true, false);
    j += 2;
  }
  if (j < qt) {
    ABODY_B0(true, false);
    ++j;
    ABODY_B1(false, true);
  } else {
    ABODY_B0(false, true);
  }

  write_o7(acco, l, pst, pb0, pb1, ll, quad, w, qt, bh, Ob);
}

// ---------------------------------------------------------------------------
// Kernel 3: out = O @ w_out^T + b_out. REVERTED to the r10/r5-verified
// version (the r13 2-phase dbuf variant regressed ~+17us: 16 MFMAs/step
// cannot hide 6 staged loads, and the extra LDS cut residency).
// ---------------------------------------------------------------------------
__global__ void __launch_bounds__(256)
k_out3(const f16* __restrict__ Ob, const f16* __restrict__ Wh,
       const float* __restrict__ bias, float* __restrict__ out)
{
  __shared__ __align__(16) f16 As[64 * 64];    //  8 KB, linear (DMA dest)
  __shared__ __align__(16) f16 Bs[128 * 64];   // 16 KB
  const int t = threadIdx.x;
  const int w = t >> 6;
  const int lane = t & 63;
  const int ll = lane & 15;
  const int quad = lane >> 4;
  const int wm = w >> 1, wn = w & 1;
  const int row0 = blockIdx.y * 64;
  const int col0 = blockIdx.x * 128;
  const int bb = row0 >> 11;
  const int s0 = row0 & (S_ - 1);

  const f32x4 fz = {0.f, 0.f, 0.f, 0.f};
  f32x4 acc[2][4];
#pragma unroll
  for (int i = 0; i < 2; ++i)
#pragma unroll
    for (int j = 0; j < 4; ++j) acc[i][j] = fz;

  const int rO = lane >> 3;
  const int gc = (lane & 7) ^ rO;
  const f16* gb2 = Wh + (size_t)(col0 + w * 8 + rO) * D_ + gc * 8;

  for (int kt = 0; kt < 16; ++kt) {
    const f16* ga2 = Ob + (((size_t)(bb * H_ + kt)) * S_ + s0 + w * 8 + rO) * HD_ + gc * 8;
    __syncthreads();
#pragma unroll
    for (int i = 0; i < 2; ++i)
      GLD16(ga2 + (size_t)(i * 32) * HD_, &As[(i * 32 + w * 8) * 64]);
#pragma unroll
    for (int i = 0; i < 4; ++i)
      GLD16(gb2 + (size_t)(i * 32) * D_ + kt * 64, &Bs[(i * 32 + w * 8) * 64]);
    __syncthreads();
#pragma unroll
    for (int kk = 0; kk < 64; kk += 32) {
      f16x8 a[2], b[4];
#pragma unroll
      for (int mt = 0; mt < 2; ++mt)
        a[mt] = *(const f16x8*)&As[swz64(wm * 32 + mt * 16 + ll, kk + quad * 8)];
#pragma unroll
      for (int nt = 0; nt < 4; ++nt)
        b[nt] = *(const f16x8*)&Bs[swz64(wn * 64 + nt * 16 + ll, kk + quad * 8)];
#pragma unroll
      for (int mt = 0; mt < 2; ++mt)
#pragma unroll
        for (int nt = 0; nt < 4; ++nt)
          acc[mt][nt] = __builtin_amdgcn_mfma_f32_16x16x32_f16(
              a[mt], b[nt], acc[mt][nt], 0, 0, 0);
    }
  }

#pragma unroll
  for (int mt = 0; mt < 2; ++mt)
#pragma unroll
    for (int r = 0; r < 4; ++r) {
      const int row = row0 + wm * 32 + mt * 16 + quad * 4 + r;
#pragma unroll
      for (int nt = 0; nt < 4; ++nt) {
        const int col = col0 + wn * 64 + nt * 16 + ll;
        out[(size_t)row * D_ + col] = fin(acc[mt][nt][r] + bias[col]);
      }
    }
}

// ---------------------------------------------------------------------------
extern "C" void kernel_launch(void* const* d_in, const int* in_sizes, int n_in,
                              void* d_out, int out_size, void* d_ws, size_t ws_size,
                              hipStream_t stream) {
  const float* x    = (const float*)d_in[0];
  const float* wqkv = (const float*)d_in[1];
  const float* wout = (const float*)d_in[2];
  const float* bout = (const float*)d_in[3];
  float* out = (float*)d_out;

  // ws: wqkvh 6M | Qb/O 8M | Kb 8M | Vt 8M | woh 2M | xh 8M (if big ws)
  char* ws = (char*)d_ws;
  f16* wqh = (f16*)(ws);
  f16* Qb  = (f16*)(ws + 6291456);
  f16* Kb  = (f16*)(ws + 14680064);
  f16* Vt  = (f16*)(ws + 23068672);
  f16* woh = (f16*)(ws + 31457280);
  const bool bigws = ws_size >= (size_t)41943040;
  f16* xh  = (f16*)(ws + 33554432);

  // RoPE table lives in d_out scratch (overwritten by k_out3 last).
  float2* tab = (float2*)((char*)d_out + 9437184);

  k_cvt3<<<2048, 256, 0, stream>>>(wqkv, wout, x, wqh, woh, xh, tab, bigws ? 1 : 0);
  if (bigws)
    k_qkv3<true><<<dim3(3 * D_ / 128, (B_ * S_) / 128), 256, 0, stream>>>(
        x, xh, wqh, tab, Qb, Kb, Vt);
  else
    k_qkv3<false><<<dim3(3 * D_ / 128, (B_ * S_) / 128), 256, 0, stream>>>(
        x, xh, wqh, tab, Qb, Kb, Vt);
  k_attn7<<<dim3(32, H_, B_), 256, 0, stream>>>(Qb, Kb, Vt, Qb /* O in place */);
  k_out3<<<dim3(D_ / 128, (B_ * S_) / 64), 256, 0, stream>>>(
      Qb, woh, bout, out);
}